// Round 1
// baseline (382.446 us; speedup 1.0000x reference)
//
#include <hip/hip_runtime.h>
#include <stdint.h>

// Boolean reservoir: B=128, T=16, N=65536, K=8, IB=256, O=10
#define NN     65536
#define KK     8
#define BB     128
#define TT     16
#define IBITS  256
#define OO     10

#define SBUF_ENTRIES (NN + IBITS)   // state + xs (xor'd shadow of nodes 0..255)
#define CHUNKS 512
#define CN     128                  // nodes per readout chunk

// ---------- helpers ----------
#if defined(__has_builtin)
#  if __has_builtin(__builtin_amdgcn_sbfe)
#    define HAVE_SBFE 1
#  endif
#endif

__device__ __forceinline__ uint32_t bmask(uint32_t w, int off) {
#ifdef HAVE_SBFE
  return (uint32_t)__builtin_amdgcn_sbfe((int)w, off, 1);  // v_bfe_i32: bit -> full mask
#else
  return 0u - ((w >> off) & 1u);
#endif
}

__device__ __forceinline__ uint4 andm(uint4 v, uint32_t m) {
  return make_uint4(v.x & m, v.y & m, v.z & m, v.w & m);
}
__device__ __forceinline__ uint4 xorv(uint4 a, uint4 b) {
  return make_uint4(a.x ^ b.x, a.y ^ b.y, a.z ^ b.z, a.w ^ b.w);
}
__device__ __forceinline__ uint4 andv(uint4 a, uint4 b) {
  return make_uint4(a.x & b.x, a.y & b.y, a.z & b.z, a.w & b.w);
}

// ---------- ANF evaluation (fully unrolled, compile-time indices only) ----------
// f(x0..x7) = XOR over subsets S of c_S * prod_{m in S} x_m
// Recursion: f = lo(c[BASE..)) ^ (x_{D-1} & hi(c[BASE+2^{D-1}..)))
template<int D, int BASE> struct Anf {
  static __device__ __forceinline__ uint4 eval(const uint32_t (&L)[8],
                                               const uint4 (&xv)[8],
                                               const uint4 &x01) {
    uint4 lo = Anf<D - 1, BASE>::eval(L, xv, x01);
    uint4 hi = Anf<D - 1, BASE + (1 << (D - 1))>::eval(L, xv, x01);
    const uint4 x = xv[D - 1];
    return make_uint4(lo.x ^ (x.x & hi.x), lo.y ^ (x.y & hi.y),
                      lo.z ^ (x.z & hi.z), lo.w ^ (x.w & hi.w));
  }
};

template<int BASE> struct Anf<2, BASE> {  // leaf: 4 coefs, vars x0,x1 (x01 precomputed)
  static __device__ __forceinline__ uint4 eval(const uint32_t (&L)[8],
                                               const uint4 (&xv)[8],
                                               const uint4 &x01) {
    const uint32_t lw = L[BASE >> 5];
    const uint32_t c0 = bmask(lw, (BASE & 31) + 0);
    const uint32_t c1 = bmask(lw, (BASE & 31) + 1);
    const uint32_t c2 = bmask(lw, (BASE & 31) + 2);
    const uint32_t c3 = bmask(lw, (BASE & 31) + 3);
    const uint4 x0 = xv[0], x1 = xv[1];
    return make_uint4(
        c0 ^ (x0.x & c1) ^ (x1.x & c2) ^ (x01.x & c3),
        c0 ^ (x0.y & c1) ^ (x1.y & c2) ^ (x01.y & c3),
        c0 ^ (x0.z & c1) ^ (x1.z & c2) ^ (x01.z & c3),
        c0 ^ (x0.w & c1) ^ (x1.w & c2) ^ (x01.w & c3));
  }
};

// ---------- pack LUT: bits -> packed 256-bit, then Mobius/ANF butterfly ----------
// thread g: node n = g>>3, word w = g&7 (8 lanes per node; shfl for cross-word dims)
__global__ __launch_bounds__(256) void pack_lut_kernel(const int* __restrict__ lut,
                                                       uint32_t* __restrict__ lutanf) {
  const int g = blockIdx.x * 256 + threadIdx.x;  // 0 .. 524287
  const int n = g >> 3, w = g & 7;
  const int4* lut4 = (const int4*)lut;
  uint32_t val = 0;
#pragma unroll
  for (int q = 0; q < 8; ++q) {
    int4 v = lut4[n * 64 + w * 8 + q];
    val |= (uint32_t)(v.x & 1) << (4 * q + 0);
    val |= (uint32_t)(v.y & 1) << (4 * q + 1);
    val |= (uint32_t)(v.z & 1) << (4 * q + 2);
    val |= (uint32_t)(v.w & 1) << (4 * q + 3);
  }
  // in-word butterfly dims 0..4: c[j] ^= c[j - 2^m] for j with bit m set
  val ^= (val << 1)  & 0xAAAAAAAAu;
  val ^= (val << 2)  & 0xCCCCCCCCu;
  val ^= (val << 4)  & 0xF0F0F0F0u;
  val ^= (val << 8)  & 0xFF00FF00u;
  val ^= (val << 16) & 0xFFFF0000u;
  // cross-word dims 5..7 via shfl within the 8-lane node group
  uint32_t p;
  p = __shfl_xor(val, 1, 64); val ^= p & (0u - (uint32_t)(w & 1));
  p = __shfl_xor(val, 2, 64); val ^= p & (0u - (uint32_t)((w >> 1) & 1));
  p = __shfl_xor(val, 4, 64); val ^= p & (0u - (uint32_t)((w >> 2) & 1));
  lutanf[g] = val;
}

// ---------- pack x: (B,T,IB) {0,1} -> xvec[t][i] = 128-bit batch vector ----------
__global__ __launch_bounds__(256) void pack_x_kernel(const int* __restrict__ x,
                                                     uint4* __restrict__ xvec) {
  const int g = blockIdx.x * 256 + threadIdx.x;  // 0..4095
  const int t = g >> 8, i = g & 255;
  uint32_t wv[4] = {0, 0, 0, 0};
#pragma unroll
  for (int b = 0; b < BB; ++b) {
    uint32_t bit = (uint32_t)(x[(b * TT + t) * IBITS + i] & 1);
    wv[b >> 5] |= bit << (b & 31);
  }
  xvec[g] = make_uint4(wv[0], wv[1], wv[2], wv[3]);
}

// ---------- pack initial state (broadcast) + xs for t=0 ----------
__global__ __launch_bounds__(256) void pack_state_kernel(const int* __restrict__ init,
                                                         const uint4* __restrict__ xvec0,
                                                         uint4* __restrict__ sA) {
  const int n = blockIdx.x * 256 + threadIdx.x;
  uint32_t m = 0u - (uint32_t)(init[n] & 1);
  uint4 s = make_uint4(m, m, m, m);
  sA[n] = s;
  if (n < IBITS) sA[NN + n] = xorv(s, xvec0[n]);
}

// ---------- one reservoir step ----------
// gather 8 neighbors (remap a<256 to xor'd shadow), mask, ANF-eval, store.
// Also writes next step's xor'd shadow for nodes < 256.
__global__ __launch_bounds__(64) void step_kernel(const uint4* __restrict__ sin,
                                                  uint4* __restrict__ sout,
                                                  const uint4* __restrict__ lutanf,
                                                  const int* __restrict__ adj,
                                                  const int* __restrict__ adjm,
                                                  const uint4* __restrict__ xnext) {
  const int n = blockIdx.x * 64 + threadIdx.x;
  const int4* adj4  = (const int4*)adj;
  const int4* adjm4 = (const int4*)adjm;
  int4 a0 = adj4[n * 2 + 0], a1 = adj4[n * 2 + 1];
  int4 m0 = adjm4[n * 2 + 0], m1 = adjm4[n * 2 + 1];
  uint4 l0 = lutanf[n * 2 + 0], l1 = lutanf[n * 2 + 1];

  const int ia[8] = {a0.x, a0.y, a0.z, a0.w, a1.x, a1.y, a1.z, a1.w};
  const int im[8] = {m0.x, m0.y, m0.z, m0.w, m1.x, m1.y, m1.z, m1.w};
  uint4 xv[8];
#pragma unroll
  for (int k = 0; k < 8; ++k) {
    int a = ia[k];
    int aa = (a < IBITS) ? (a + NN) : a;  // nodes<256: read xor'd shadow
    uint4 g = sin[aa];
    // neighbor k has weight 2^(7-k) -> ANF variable x_{7-k}
    xv[7 - k] = andm(g, 0u - (uint32_t)(im[k] & 1));
  }
  const uint32_t L[8] = {l0.x, l0.y, l0.z, l0.w, l1.x, l1.y, l1.z, l1.w};
  const uint4 x01 = andv(xv[0], xv[1]);
  uint4 r = Anf<8, 0>::eval(L, xv, x01);
  sout[n] = r;
  if (xnext != nullptr && n < IBITS) {
    sout[NN + n] = xorv(r, xnext[n]);  // pre-xor'd shadow for next step's gathers
  }
}

// ---------- readout partials: chunk of CN nodes, thread = batch element ----------
__global__ __launch_bounds__(128) void readout_kernel(const uint4* __restrict__ state,
                                                      const float* __restrict__ w,
                                                      float* __restrict__ part) {
  __shared__ uint4 sst[CN];
  const int chunk = blockIdx.x;
  const int b = threadIdx.x;
  sst[b] = state[chunk * CN + b];
  __syncthreads();
  const uint32_t* sw = (const uint32_t*)sst;
  const int word = b >> 5, sh = b & 31;
  float acc[OO];
#pragma unroll
  for (int o = 0; o < OO; ++o) acc[o] = 0.f;
  for (int nl = 0; nl < CN; ++nl) {
    uint32_t m = 0u - ((sw[nl * 4 + word] >> sh) & 1u);
#pragma unroll
    for (int o = 0; o < OO; ++o) {
      uint32_t wv = __float_as_uint(w[o * NN + chunk * CN + nl]) & m;
      acc[o] += __uint_as_float(wv);
    }
  }
#pragma unroll
  for (int o = 0; o < OO; ++o) part[chunk * (BB * OO) + b * OO + o] = acc[o];
}

// ---------- finalize: sum partials + bias, sigmoid ----------
__global__ __launch_bounds__(256) void finalize_kernel(const float* __restrict__ part,
                                                       const float* __restrict__ bias,
                                                       float* __restrict__ out) {
  const int i = blockIdx.x * 256 + threadIdx.x;
  if (i >= BB * OO) return;
  const int o = i % OO;
  float s = bias[o];
  for (int c = 0; c < CHUNKS; ++c) s += part[c * (BB * OO) + i];
  out[i] = 1.f / (1.f + __expf(-s));
}

// ---------- launch ----------
extern "C" void kernel_launch(void* const* d_in, const int* in_sizes, int n_in,
                              void* d_out, int out_size, void* d_ws, size_t ws_size,
                              hipStream_t stream) {
  const int* x     = (const int*)d_in[0];
  const int* adj   = (const int*)d_in[1];
  const int* adjm  = (const int*)d_in[2];
  const int* lut   = (const int*)d_in[3];
  const int* init  = (const int*)d_in[4];
  // d_in[5] = w_in (arange(IB) per setup; folded into the xs-shadow scheme)
  const float* wro = (const float*)d_in[6];
  const float* bro = (const float*)d_in[7];
  float* out = (float*)d_out;

  char* ws = (char*)d_ws;
  const size_t SBUF = (size_t)SBUF_ENTRIES * 16;
  uint4* sA = (uint4*)(ws);
  uint4* sB = (uint4*)(ws + SBUF);
  uint4* xvec = (uint4*)(ws + 2 * SBUF);
  uint32_t* lutanf = (uint32_t*)(ws + 2 * SBUF + (size_t)TT * IBITS * 16);
  float* part = (float*)(ws + 2 * SBUF + (size_t)TT * IBITS * 16 + (size_t)NN * 32);

  hipLaunchKernelGGL(pack_lut_kernel, dim3((NN * KK) / 256), dim3(256), 0, stream, lut, lutanf);
  hipLaunchKernelGGL(pack_x_kernel, dim3((TT * IBITS) / 256), dim3(256), 0, stream, x, xvec);
  hipLaunchKernelGGL(pack_state_kernel, dim3(NN / 256), dim3(256), 0, stream, init, xvec, sA);

  for (int t = 0; t < TT; ++t) {
    const uint4* sin = (t & 1) ? sB : sA;
    uint4* sout      = (t & 1) ? sA : sB;
    const uint4* xn  = (t + 1 < TT) ? (xvec + (size_t)(t + 1) * IBITS) : nullptr;
    hipLaunchKernelGGL(step_kernel, dim3(NN / 64), dim3(64), 0, stream,
                       sin, sout, (const uint4*)lutanf, adj, adjm, xn);
  }
  // T=16 steps: t=15 is odd -> final state in sA
  hipLaunchKernelGGL(readout_kernel, dim3(CHUNKS), dim3(128), 0, stream, sA, wro, part);
  hipLaunchKernelGGL(finalize_kernel, dim3((BB * OO + 255) / 256), dim3(256), 0, stream,
                     part, bro, out);
}

// Round 2
// 271.792 us; speedup vs baseline: 1.4071x; 1.4071x over previous
//
#include <hip/hip_runtime.h>
#include <stdint.h>

// Boolean reservoir: B=128, T=16, N=65536, K=8, IB=256, O=10
#define NN     65536
#define KK     8
#define BB     128
#define TT     16
#define IBITS  256
#define OO     10

#define ZIDX         (NN + IBITS)        // always-zero sentinel entry
#define SBUF_ENTRIES (NN + IBITS + 1)    // state + xor'd shadow + zero sentinel
#define RCHUNKS 512
#define RNODES  128                      // nodes per readout block

// ---------- helpers ----------
#if defined(__has_builtin)
#  if __has_builtin(__builtin_amdgcn_sbfe)
#    define HAVE_SBFE 1
#  endif
#endif

__device__ __forceinline__ uint32_t bmask(uint32_t w, int off) {
#ifdef HAVE_SBFE
  return (uint32_t)__builtin_amdgcn_sbfe((int)w, off, 1);  // bit -> full mask
#else
  return 0u - ((w >> off) & 1u);
#endif
}

__device__ __forceinline__ uint4 xorv(uint4 a, uint4 b) {
  return make_uint4(a.x ^ b.x, a.y ^ b.y, a.z ^ b.z, a.w ^ b.w);
}

// ---------- scalar (1-word) ANF evaluation, fully unrolled ----------
template<int D, int BASE> struct Anf1 {
  static __device__ __forceinline__ uint32_t eval(const uint32_t (&L)[8],
                                                  const uint32_t (&xv)[8],
                                                  uint32_t x01) {
    uint32_t lo = Anf1<D - 1, BASE>::eval(L, xv, x01);
    uint32_t hi = Anf1<D - 1, BASE + (1 << (D - 1))>::eval(L, xv, x01);
    return lo ^ (xv[D - 1] & hi);
  }
};
template<int BASE> struct Anf1<2, BASE> {
  static __device__ __forceinline__ uint32_t eval(const uint32_t (&L)[8],
                                                  const uint32_t (&xv)[8],
                                                  uint32_t x01) {
    const uint32_t lw = L[BASE >> 5];
    const uint32_t c0 = bmask(lw, (BASE & 31) + 0);
    const uint32_t c1 = bmask(lw, (BASE & 31) + 1);
    const uint32_t c2 = bmask(lw, (BASE & 31) + 2);
    const uint32_t c3 = bmask(lw, (BASE & 31) + 3);
    return c0 ^ (xv[0] & c1) ^ (xv[1] & c2) ^ (x01 & c3);
  }
};

// ---------- pack LUT -> bit-packed truth table -> ANF (Mobius) coefficients ----------
__global__ __launch_bounds__(256) void pack_lut_kernel(const int* __restrict__ lut,
                                                       uint32_t* __restrict__ lutanf) {
  const int g = blockIdx.x * 256 + threadIdx.x;  // 0 .. 524287
  const int n = g >> 3, w = g & 7;
  const int4* lut4 = (const int4*)lut;
  uint32_t val = 0;
#pragma unroll
  for (int q = 0; q < 8; ++q) {
    int4 v = lut4[n * 64 + w * 8 + q];
    val |= (uint32_t)(v.x & 1) << (4 * q + 0);
    val |= (uint32_t)(v.y & 1) << (4 * q + 1);
    val |= (uint32_t)(v.z & 1) << (4 * q + 2);
    val |= (uint32_t)(v.w & 1) << (4 * q + 3);
  }
  val ^= (val << 1)  & 0xAAAAAAAAu;
  val ^= (val << 2)  & 0xCCCCCCCCu;
  val ^= (val << 4)  & 0xF0F0F0F0u;
  val ^= (val << 8)  & 0xFF00FF00u;
  val ^= (val << 16) & 0xFFFF0000u;
  uint32_t p;
  p = __shfl_xor(val, 1, 64); val ^= p & (0u - (uint32_t)(w & 1));
  p = __shfl_xor(val, 2, 64); val ^= p & (0u - (uint32_t)((w >> 1) & 1));
  p = __shfl_xor(val, 4, 64); val ^= p & (0u - (uint32_t)((w >> 2) & 1));
  lutanf[g] = val;
}

// ---------- fold adj + mask + shadow-remap into one index array ----------
__global__ __launch_bounds__(256) void pack_madj_kernel(const int* __restrict__ adj,
                                                        const int* __restrict__ adjm,
                                                        int* __restrict__ madj) {
  const int g = blockIdx.x * 256 + threadIdx.x;  // 0 .. NN*KK-1
  int a = adj[g];
  int m = adjm[g] & 1;
  madj[g] = m ? ((a < IBITS) ? a + NN : a) : ZIDX;
}

// ---------- pack x: (B,T,IB) -> xvec[t][i] 128-bit batch vectors (word-split) ----------
__global__ __launch_bounds__(256) void pack_x_kernel(const int* __restrict__ x,
                                                     uint32_t* __restrict__ xvecw) {
  const int g = blockIdx.x * 256 + threadIdx.x;  // 0 .. TT*IBITS*4-1 = 16383
  const int t = g >> 10, rest = g & 1023, i = rest >> 2, bq = rest & 3;
  uint32_t wv = 0;
#pragma unroll
  for (int bl = 0; bl < 32; ++bl) {
    int b = bq * 32 + bl;
    uint32_t bit = (uint32_t)(x[(b * TT + t) * IBITS + i] & 1);
    wv |= bit << bl;
  }
  xvecw[(t * IBITS + i) * 4 + bq] = wv;
}

// ---------- pack initial state + t=0 shadow + zero sentinels ----------
__global__ __launch_bounds__(256) void pack_state_kernel(const int* __restrict__ init,
                                                         const uint4* __restrict__ xvec0,
                                                         uint4* __restrict__ sA,
                                                         uint4* __restrict__ sB) {
  const int n = blockIdx.x * 256 + threadIdx.x;
  uint32_t m = 0u - (uint32_t)(init[n] & 1);
  uint4 s = make_uint4(m, m, m, m);
  sA[n] = s;
  if (n < IBITS) sA[NN + n] = xorv(s, xvec0[n]);
  if (n == 0) {
    uint4 z = make_uint4(0, 0, 0, 0);
    sA[ZIDX] = z;
    sB[ZIDX] = z;
  }
}

// ---------- one reservoir step: 1 batch-word per thread (4 waves/SIMD) ----------
__global__ __launch_bounds__(256) void step_kernel(const uint32_t* __restrict__ sinw,
                                                   uint32_t* __restrict__ soutw,
                                                   const uint4* __restrict__ lutanf,
                                                   const int* __restrict__ madj,
                                                   const uint32_t* __restrict__ xnextw) {
  const int g = blockIdx.x * 256 + threadIdx.x;  // 0 .. 262143
  const int n = g >> 2, w = g & 3;
  const int4* madj4 = (const int4*)madj;
  int4 a0 = madj4[n * 2 + 0], a1 = madj4[n * 2 + 1];
  uint4 l0 = lutanf[n * 2 + 0], l1 = lutanf[n * 2 + 1];
  const int ia[8] = {a0.x, a0.y, a0.z, a0.w, a1.x, a1.y, a1.z, a1.w};
  uint32_t xv[8];
#pragma unroll
  for (int k = 0; k < 8; ++k) {
    // neighbor k has weight 2^(7-k) -> ANF variable x_{7-k}
    xv[7 - k] = sinw[(ia[k] << 2) + w];
  }
  const uint32_t L[8] = {l0.x, l0.y, l0.z, l0.w, l1.x, l1.y, l1.z, l1.w};
  const uint32_t x01 = xv[0] & xv[1];
  uint32_t r = Anf1<8, 0>::eval(L, xv, x01);
  soutw[(n << 2) + w] = r;
  if (xnextw != nullptr && n < IBITS) {
    soutw[((NN + n) << 2) + w] = r ^ xnextw[(n << 2) + w];  // next step's shadow
  }
}

// ---------- readout partials: LDS-staged w + state, (b, o-half) threads ----------
__global__ __launch_bounds__(256) void readout_kernel(const uint32_t* __restrict__ statew,
                                                      const float* __restrict__ w,
                                                      float* __restrict__ part) {
  __shared__ uint32_t sw[64 * 4];
  __shared__ float wsm[OO * 64];
  const int c = blockIdx.x;
  const int t = threadIdx.x;
  const int b = t & 127, oh = t >> 7;
  const int word = b >> 5, sh = b & 31;
  float acc[5] = {0.f, 0.f, 0.f, 0.f, 0.f};
  for (int s = 0; s < 2; ++s) {
    const int base = c * RNODES + s * 64;
    __syncthreads();
    sw[t] = statew[base * 4 + t];
#pragma unroll
    for (int r = 0; r < 3; ++r) {
      int idx = r * 256 + t;
      if (idx < OO * 64) wsm[idx] = w[(idx >> 6) * NN + base + (idx & 63)];
    }
    __syncthreads();
#pragma unroll 8
    for (int j = 0; j < 64; ++j) {
      uint32_t m = 0u - ((sw[j * 4 + word] >> sh) & 1u);
#pragma unroll
      for (int q = 0; q < 5; ++q) {
        uint32_t wv = __float_as_uint(wsm[(oh * 5 + q) * 64 + j]) & m;
        acc[q] += __uint_as_float(wv);
      }
    }
  }
#pragma unroll
  for (int q = 0; q < 5; ++q)
    part[(c * BB + b) * OO + oh * 5 + q] = acc[q];
}

// ---------- finalize: block per (b,o), tree-reduce 512 partials ----------
__global__ __launch_bounds__(256) void finalize_kernel(const float* __restrict__ part,
                                                       const float* __restrict__ bias,
                                                       float* __restrict__ out) {
  __shared__ float red[256];
  const int i = blockIdx.x;  // 0 .. BB*OO-1
  const int b = i / OO, o = i % OO;
  const int t = threadIdx.x;
  float s = part[(t * BB + b) * OO + o] + part[((t + 256) * BB + b) * OO + o];
  red[t] = s;
  __syncthreads();
  for (int h = 128; h > 0; h >>= 1) {
    if (t < h) red[t] += red[t + h];
    __syncthreads();
  }
  if (t == 0) out[b * OO + o] = 1.f / (1.f + __expf(-(red[0] + bias[o])));
}

// ---------- launch ----------
extern "C" void kernel_launch(void* const* d_in, const int* in_sizes, int n_in,
                              void* d_out, int out_size, void* d_ws, size_t ws_size,
                              hipStream_t stream) {
  const int* x    = (const int*)d_in[0];
  const int* adj  = (const int*)d_in[1];
  const int* adjm = (const int*)d_in[2];
  const int* lut  = (const int*)d_in[3];
  const int* init = (const int*)d_in[4];
  // d_in[5] = w_in (arange(IB); folded into the shadow scheme)
  const float* wro = (const float*)d_in[6];
  const float* bro = (const float*)d_in[7];
  float* out = (float*)d_out;

  char* ws = (char*)d_ws;
  const size_t SBUF = (size_t)SBUF_ENTRIES * 16;
  uint4* sA       = (uint4*)(ws);
  uint4* sB       = (uint4*)(ws + SBUF);
  uint32_t* xvecw = (uint32_t*)(ws + 2 * SBUF);
  uint32_t* lutanf = (uint32_t*)(ws + 2 * SBUF + (size_t)TT * IBITS * 16);
  int* madj       = (int*)(ws + 2 * SBUF + (size_t)TT * IBITS * 16 + (size_t)NN * 32);
  float* part     = (float*)(ws + 2 * SBUF + (size_t)TT * IBITS * 16 + (size_t)NN * 64);

  hipLaunchKernelGGL(pack_lut_kernel, dim3((NN * KK) / 256), dim3(256), 0, stream, lut, lutanf);
  hipLaunchKernelGGL(pack_x_kernel, dim3((TT * IBITS * 4) / 256), dim3(256), 0, stream, x, xvecw);
  hipLaunchKernelGGL(pack_madj_kernel, dim3((NN * KK) / 256), dim3(256), 0, stream, adj, adjm, madj);
  hipLaunchKernelGGL(pack_state_kernel, dim3(NN / 256), dim3(256), 0, stream,
                     init, (const uint4*)xvecw, sA, sB);

  for (int t = 0; t < TT; ++t) {
    const uint32_t* sin = (const uint32_t*)((t & 1) ? sB : sA);
    uint32_t* sout      = (uint32_t*)((t & 1) ? sA : sB);
    const uint32_t* xn  = (t + 1 < TT) ? (xvecw + (size_t)(t + 1) * IBITS * 4) : nullptr;
    hipLaunchKernelGGL(step_kernel, dim3((NN * 4) / 256), dim3(256), 0, stream,
                       sin, sout, (const uint4*)lutanf, madj, xn);
  }
  // T=16 steps: final state in sA
  hipLaunchKernelGGL(readout_kernel, dim3(RCHUNKS), dim3(256), 0, stream,
                     (const uint32_t*)sA, wro, part);
  hipLaunchKernelGGL(finalize_kernel, dim3(BB * OO), dim3(256), 0, stream, part, bro, out);
}